// Round 2
// baseline (7544.558 us; speedup 1.0000x reference)
//
#include <hip/hip_runtime.h>
#include <hip/hip_fp16.h>

#define N 4096
#define KX 3072
#define KZ 128
#define NB (N / 64)
#define NTRI (NB * (NB + 1) / 2)

// ---------- storage-type helpers (float or half D matrices) ----------
__device__ __forceinline__ float4 loadRow4(const float* p) { return *(const float4*)p; }
__device__ __forceinline__ float4 loadRow4(const __half* p) {
  __half2 a = *(const __half2*)p;
  __half2 b = *(const __half2*)(p + 2);
  float2 fa = __half22float2(a), fb = __half22float2(b);
  return make_float4(fa.x, fa.y, fb.x, fb.y);
}
__device__ __forceinline__ void storeD(float* p, float v) { *p = v; }
__device__ __forceinline__ void storeD(__half* p, float v) { *p = __float2half(v); }
__device__ __forceinline__ float toF(float v) { return v; }
__device__ __forceinline__ float toF(__half v) { return __half2float(v); }

// ---------- row squared norms ----------
__global__ __launch_bounds__(256) void sqnorm_kernel(const float* __restrict__ X, int K,
                                                     float* __restrict__ sq) {
  int row = blockIdx.x;
  const float4* xr = (const float4*)(X + (size_t)row * K);
  float s = 0.f;
  int n4 = K >> 2;
  for (int i = threadIdx.x; i < n4; i += 256) {
    float4 v = xr[i];
    s += v.x * v.x + v.y * v.y + v.z * v.z + v.w * v.w;
  }
  for (int off = 32; off > 0; off >>= 1) s += __shfl_down(s, off);
  __shared__ float wsum[4];
  int lane = threadIdx.x & 63, w = threadIdx.x >> 6;
  if (lane == 0) wsum[w] = s;
  __syncthreads();
  if (threadIdx.x == 0) {
    float t = 0.f;
    #pragma unroll
    for (int i = 0; i < 4; ++i) t += wsum[i];
    sq[row] = t;
  }
}

// ---------- fused distance GEMM: D = sqrt(relu(sq_i + sq_j - 2*X@X^T)) ----------
template <typename T>
__global__ __launch_bounds__(256) void dist_gemm_kernel(const float* __restrict__ X, int K,
                                                        const float* __restrict__ sq,
                                                        T* __restrict__ D) {
  int t = blockIdx.x;
  int br = (int)((sqrtf(8.0f * (float)t + 1.0f) - 1.0f) * 0.5f);
  while ((br + 1) * (br + 2) / 2 <= t) ++br;
  while (br * (br + 1) / 2 > t) --br;
  int bc = t - br * (br + 1) / 2;
  int i0 = br * 64, j0 = bc * 64;

  __shared__ float As[32][68];
  __shared__ float Bs[32][68];

  int tid = threadIdx.x;
  int tx = tid & 15, ty = tid >> 4;

  float acc[4][4] = {};

  for (int k0 = 0; k0 < K; k0 += 32) {
    #pragma unroll
    for (int u = 0; u < 2; ++u) {
      int f = tid + u * 256;   // 0..511
      int m = f >> 3;          // 0..63
      int kc = (f & 7) * 4;    // 0..28
      float4 a = *(const float4*)(X + (size_t)(i0 + m) * K + k0 + kc);
      As[kc + 0][m] = a.x; As[kc + 1][m] = a.y; As[kc + 2][m] = a.z; As[kc + 3][m] = a.w;
      float4 b = *(const float4*)(X + (size_t)(j0 + m) * K + k0 + kc);
      Bs[kc + 0][m] = b.x; Bs[kc + 1][m] = b.y; Bs[kc + 2][m] = b.z; Bs[kc + 3][m] = b.w;
    }
    __syncthreads();
    #pragma unroll
    for (int kk = 0; kk < 32; ++kk) {
      float4 a = *(const float4*)&As[kk][ty * 4];
      float4 b = *(const float4*)&Bs[kk][tx * 4];
      float av[4] = {a.x, a.y, a.z, a.w};
      float bv[4] = {b.x, b.y, b.z, b.w};
      #pragma unroll
      for (int i = 0; i < 4; ++i)
        #pragma unroll
        for (int j = 0; j < 4; ++j)
          acc[i][j] = fmaf(av[i], bv[j], acc[i][j]);
    }
    __syncthreads();
  }

  #pragma unroll
  for (int i = 0; i < 4; ++i) {
    int gi = i0 + ty * 4 + i;
    float sqi = sq[gi];
    #pragma unroll
    for (int j = 0; j < 4; ++j) {
      int gj = j0 + tx * 4 + j;
      float d2 = sqi + sq[gj] - 2.0f * acc[i][j];
      float d = sqrtf(fmaxf(d2, 0.0f));
      storeD(&D[(size_t)gi * N + gj], d);
      storeD(&D[(size_t)gj * N + gi], d);
    }
  }
}

// ---------- MST (exact replication of the reference scan) ----------
// block 0 -> Dx, block 1 -> Dz. 256 threads (4 waves), 16 consecutive nodes/thread.
// Rationale vs 1024-thread version: 4x less LDS-pipe traffic for the shuffle
// butterflies, 4-wave barrier instead of 16-wave, one wave per SIMD (no issue
// contention). The cross-wave stage is a 3-compare serial combine of 4 LDS
// slots (broadcast reads).
template <typename T>
__global__ __launch_bounds__(256) void mst_kernel(const T* __restrict__ Dx,
                                                  const T* __restrict__ Dz,
                                                  int2* __restrict__ ex,
                                                  int2* __restrict__ ez) {
  const T* __restrict__ D = (blockIdx.x == 0) ? Dx : Dz;
  int2* __restrict__ edges = (blockIdx.x == 0) ? ex : ez;
  const float INF = __builtin_inff();

  int tid = threadIdx.x;      // 0..255
  int lane = tid & 63;
  int w = tid >> 6;           // wave 0..3
  int base = tid * 16;        // nodes [base, base+16)

  float md[16];
  int par[16];
  #pragma unroll
  for (int q = 0; q < 16; ++q) par[q] = 0;
  {
    #pragma unroll
    for (int u = 0; u < 4; ++u) {
      float4 r = loadRow4(D + base + u * 4);
      md[u * 4 + 0] = r.x; md[u * 4 + 1] = r.y; md[u * 4 + 2] = r.z; md[u * 4 + 3] = r.w;
    }
    if (tid == 0) md[0] = INF;  // node 0 starts in tree
  }

  __shared__ float swv[2][4];
  __shared__ int swi[2][4];

  for (int step = 0; step < N - 1; ++step) {
    // ---- thread-local argmin over 16 values: 4-deep pairwise tree,
    //      keep-left-on-tie => lowest index wins ties.
    float tv[8]; int ti[8];
    #pragma unroll
    for (int q = 0; q < 8; ++q) {
      bool lt = md[q + 8] < md[q];
      tv[q] = lt ? md[q + 8] : md[q];
      ti[q] = lt ? (q + 8) : q;
    }
    #pragma unroll
    for (int q = 0; q < 4; ++q) {
      bool lt = tv[q + 4] < tv[q];
      tv[q] = lt ? tv[q + 4] : tv[q];
      ti[q] = lt ? ti[q + 4] : ti[q];
    }
    #pragma unroll
    for (int q = 0; q < 2; ++q) {
      bool lt = tv[q + 2] < tv[q];
      tv[q] = lt ? tv[q + 2] : tv[q];
      ti[q] = lt ? ti[q + 2] : ti[q];
    }
    bool lt0 = tv[1] < tv[0];
    float bv = lt0 ? tv[1] : tv[0];
    int bi = base + (lt0 ? ti[1] : ti[0]);

    // ---- wave butterfly argmin (64 lanes)
    #pragma unroll
    for (int m = 32; m; m >>= 1) {
      float ov = __shfl_xor(bv, m);
      int oi = __shfl_xor(bi, m);
      if (ov < bv || (ov == bv && oi < bi)) { bv = ov; bi = oi; }
    }

    // ---- cross-wave combine via 4 LDS slots, parity double-buffered,
    //      single barrier per step.
    int p = step & 1;
    if (lane == 0) { swv[p][w] = bv; swi[p][w] = bi; }
    __syncthreads();
    bv = swv[p][0]; bi = swi[p][0];
    #pragma unroll
    for (int k = 1; k < 4; ++k) {
      float ov = swv[p][k]; int oi = swi[p][k];
      if (ov < bv || (ov == bv && oi < bi)) { bv = ov; bi = oi; }
    }
    int j = bi;
    int jt = j >> 4;

    // record edge with parent BEFORE this step's updates (matches reference)
    if (jt == tid) edges[step] = make_int2(par[j & 15], j);

    // ---- load row j (64B/thread, coalesced) and min-update
    const T* row = D + (size_t)j * N + base;
    float rv[16];
    #pragma unroll
    for (int u = 0; u < 4; ++u) {
      float4 r = loadRow4(row + u * 4);
      rv[u * 4 + 0] = r.x; rv[u * 4 + 1] = r.y; rv[u * 4 + 2] = r.z; rv[u * 4 + 3] = r.w;
    }
    #pragma unroll
    for (int q = 0; q < 16; ++q)
      if (rv[q] < md[q]) { md[q] = rv[q]; par[q] = j; }
    if (jt == tid) md[j & 15] = INF;  // after min-update, like .at[j].set(inf)
  }
}

// ---------- final loss ----------
template <typename T>
__global__ __launch_bounds__(1024) void loss_kernel(const T* __restrict__ Dx,
                                                    const T* __restrict__ Dz,
                                                    const int2* __restrict__ ex,
                                                    const int2* __restrict__ ez,
                                                    float* __restrict__ out) {
  int tid = threadIdx.x;
  float s = 0.f;
  const int M = N - 1;
  for (int e = tid; e < 2 * M; e += 1024) {
    int2 uv = (e < M) ? ex[e] : ez[e - M];
    size_t off = (size_t)uv.x * N + uv.y;
    float dx = toF(Dx[off]);
    float dz = toF(Dz[off]);
    float d = dx - dz;
    s += d * d;
  }
  for (int off = 32; off > 0; off >>= 1) s += __shfl_down(s, off);
  __shared__ float wsum[16];
  int lane = tid & 63, w = tid >> 6;
  if (lane == 0) wsum[w] = s;
  __syncthreads();
  if (tid == 0) {
    float t = 0.f;
    #pragma unroll
    for (int i = 0; i < 16; ++i) t += wsum[i];
    out[0] = 0.5f * t;
  }
}

// ---------- launch ----------
template <typename T>
static void launch_all(const float* x, const float* z, char* ws, float* out,
                       hipStream_t stream) {
  T* Dx = (T*)ws;
  T* Dz = Dx + (size_t)N * N;
  float* sqx = (float*)(Dz + (size_t)N * N);
  float* sqz = sqx + N;
  int2* ex = (int2*)(sqz + N);
  int2* ez = ex + (N - 1);

  sqnorm_kernel<<<N, 256, 0, stream>>>(x, KX, sqx);
  sqnorm_kernel<<<N, 256, 0, stream>>>(z, KZ, sqz);
  dist_gemm_kernel<T><<<NTRI, 256, 0, stream>>>(x, KX, sqx, Dx);
  dist_gemm_kernel<T><<<NTRI, 256, 0, stream>>>(z, KZ, sqz, Dz);
  mst_kernel<T><<<2, 256, 0, stream>>>(Dx, Dz, ex, ez);
  loss_kernel<T><<<1, 1024, 0, stream>>>(Dx, Dz, ex, ez, out);
}

extern "C" void kernel_launch(void* const* d_in, const int* in_sizes, int n_in,
                              void* d_out, int out_size, void* d_ws, size_t ws_size,
                              hipStream_t stream) {
  const float* x = (const float*)d_in[0];
  const float* z = (const float*)d_in[1];
  float* out = (float*)d_out;
  char* ws = (char*)d_ws;

  size_t need_f32 = (size_t)2 * N * N * sizeof(float) + 2 * N * sizeof(float)
                  + (size_t)2 * (N - 1) * sizeof(int2);
  if (ws_size >= need_f32) {
    launch_all<float>(x, z, ws, out, stream);
  } else {
    launch_all<__half>(x, z, ws, out, stream);
  }
}

// Round 3
// 6148.198 us; speedup vs baseline: 1.2271x; 1.2271x over previous
//
#include <hip/hip_runtime.h>
#include <hip/hip_fp16.h>

#define N 4096
#define KX 3072
#define KZ 128
#define NB (N / 64)
#define NTRI (NB * (NB + 1) / 2)

// ---------- storage-type helpers (float or half D matrices) ----------
__device__ __forceinline__ float4 loadRow4(const float* p) { return *(const float4*)p; }
__device__ __forceinline__ float4 loadRow4(const __half* p) {
  __half2 a = *(const __half2*)p;
  __half2 b = *(const __half2*)(p + 2);
  float2 fa = __half22float2(a), fb = __half22float2(b);
  return make_float4(fa.x, fa.y, fb.x, fb.y);
}
__device__ __forceinline__ void storeD(float* p, float v) { *p = v; }
__device__ __forceinline__ void storeD(__half* p, float v) { *p = __float2half(v); }
__device__ __forceinline__ float toF(float v) { return v; }
__device__ __forceinline__ float toF(__half v) { return __half2float(v); }

// ---------- row squared norms ----------
__global__ __launch_bounds__(256) void sqnorm_kernel(const float* __restrict__ X, int K,
                                                     float* __restrict__ sq) {
  int row = blockIdx.x;
  const float4* xr = (const float4*)(X + (size_t)row * K);
  float s = 0.f;
  int n4 = K >> 2;
  for (int i = threadIdx.x; i < n4; i += 256) {
    float4 v = xr[i];
    s += v.x * v.x + v.y * v.y + v.z * v.z + v.w * v.w;
  }
  for (int off = 32; off > 0; off >>= 1) s += __shfl_down(s, off);
  __shared__ float wsum[4];
  int lane = threadIdx.x & 63, w = threadIdx.x >> 6;
  if (lane == 0) wsum[w] = s;
  __syncthreads();
  if (threadIdx.x == 0) {
    float t = 0.f;
    #pragma unroll
    for (int i = 0; i < 4; ++i) t += wsum[i];
    sq[row] = t;
  }
}

// ---------- fused distance GEMM: D = sqrt(relu(sq_i + sq_j - 2*X@X^T)) ----------
template <typename T>
__global__ __launch_bounds__(256) void dist_gemm_kernel(const float* __restrict__ X, int K,
                                                        const float* __restrict__ sq,
                                                        T* __restrict__ D) {
  int t = blockIdx.x;
  int br = (int)((sqrtf(8.0f * (float)t + 1.0f) - 1.0f) * 0.5f);
  while ((br + 1) * (br + 2) / 2 <= t) ++br;
  while (br * (br + 1) / 2 > t) --br;
  int bc = t - br * (br + 1) / 2;
  int i0 = br * 64, j0 = bc * 64;

  __shared__ float As[32][68];
  __shared__ float Bs[32][68];

  int tid = threadIdx.x;
  int tx = tid & 15, ty = tid >> 4;

  float acc[4][4] = {};

  for (int k0 = 0; k0 < K; k0 += 32) {
    #pragma unroll
    for (int u = 0; u < 2; ++u) {
      int f = tid + u * 256;   // 0..511
      int m = f >> 3;          // 0..63
      int kc = (f & 7) * 4;    // 0..28
      float4 a = *(const float4*)(X + (size_t)(i0 + m) * K + k0 + kc);
      As[kc + 0][m] = a.x; As[kc + 1][m] = a.y; As[kc + 2][m] = a.z; As[kc + 3][m] = a.w;
      float4 b = *(const float4*)(X + (size_t)(j0 + m) * K + k0 + kc);
      Bs[kc + 0][m] = b.x; Bs[kc + 1][m] = b.y; Bs[kc + 2][m] = b.z; Bs[kc + 3][m] = b.w;
    }
    __syncthreads();
    #pragma unroll
    for (int kk = 0; kk < 32; ++kk) {
      float4 a = *(const float4*)&As[kk][ty * 4];
      float4 b = *(const float4*)&Bs[kk][tx * 4];
      float av[4] = {a.x, a.y, a.z, a.w};
      float bv[4] = {b.x, b.y, b.z, b.w};
      #pragma unroll
      for (int i = 0; i < 4; ++i)
        #pragma unroll
        for (int j = 0; j < 4; ++j)
          acc[i][j] = fmaf(av[i], bv[j], acc[i][j]);
    }
    __syncthreads();
  }

  #pragma unroll
  for (int i = 0; i < 4; ++i) {
    int gi = i0 + ty * 4 + i;
    float sqi = sq[gi];
    #pragma unroll
    for (int j = 0; j < 4; ++j) {
      int gj = j0 + tx * 4 + j;
      float d2 = sqi + sq[gj] - 2.0f * acc[i][j];
      float d = sqrtf(fmaxf(d2, 0.0f));
      storeD(&D[(size_t)gi * N + gj], d);
      storeD(&D[(size_t)gj * N + gi], d);
    }
  }
}

// ---------- MST (exact replication of the reference scan) ----------
// block 0 -> Dx, block 1 -> Dz. 256 threads (4 waves), 16 consecutive nodes/thread.
// ALL per-thread state statically indexed (runtime-indexed arrays go to scratch
// -> that was the 3500-cycle/step floor in rounds 1-2). Argmin uses a packed
// u64 key (dist_bits<<32 | idx): valid since d>=0, gives exact first-index
// tie-break, and makes each butterfly stage a single 64-bit min.
template <typename T>
__global__ __launch_bounds__(256) void mst_kernel(const T* __restrict__ Dx,
                                                  const T* __restrict__ Dz,
                                                  int2* __restrict__ ex,
                                                  int2* __restrict__ ez) {
  const T* __restrict__ D = (blockIdx.x == 0) ? Dx : Dz;
  int2* __restrict__ edges = (blockIdx.x == 0) ? ex : ez;
  const float INF = __builtin_inff();

  int tid = threadIdx.x;      // 0..255
  int lane = tid & 63;
  int w = tid >> 6;           // wave 0..3
  int base = tid * 16;        // nodes [base, base+16)

  float md[16];
  int par[16];
  #pragma unroll
  for (int q = 0; q < 16; ++q) par[q] = 0;
  {
    #pragma unroll
    for (int u = 0; u < 4; ++u) {
      float4 r = loadRow4(D + base + u * 4);
      md[u * 4 + 0] = r.x; md[u * 4 + 1] = r.y; md[u * 4 + 2] = r.z; md[u * 4 + 3] = r.w;
    }
    if (tid == 0) md[0] = INF;  // node 0 starts in tree
  }

  __shared__ unsigned long long skey[2][4];

  for (int step = 0; step < N - 1; ++step) {
    // ---- thread-local argmin over 16 values: 4-deep pairwise tree,
    //      keep-left-on-tie => lowest index wins ties (left index < right).
    float tv[8]; int ti[8];
    #pragma unroll
    for (int q = 0; q < 8; ++q) {
      bool lt = md[q + 8] < md[q];
      tv[q] = lt ? md[q + 8] : md[q];
      ti[q] = lt ? (q + 8) : q;
    }
    #pragma unroll
    for (int q = 0; q < 4; ++q) {
      bool lt = tv[q + 4] < tv[q];
      tv[q] = lt ? tv[q + 4] : tv[q];
      ti[q] = lt ? ti[q + 4] : ti[q];
    }
    #pragma unroll
    for (int q = 0; q < 2; ++q) {
      bool lt = tv[q + 2] < tv[q];
      tv[q] = lt ? tv[q + 2] : tv[q];
      ti[q] = lt ? ti[q + 2] : ti[q];
    }
    bool lt0 = tv[1] < tv[0];
    float bv = lt0 ? tv[1] : tv[0];
    int bi = base + (lt0 ? ti[1] : ti[0]);

    // ---- packed key: d >= 0 so float bits are order-monotonic as uint.
    unsigned long long key =
        ((unsigned long long)__float_as_uint(bv) << 32) | (unsigned)bi;

    // ---- wave butterfly min (64 lanes), single u64 compare per stage
    #pragma unroll
    for (int m = 32; m; m >>= 1) {
      unsigned long long ok = __shfl_xor(key, m);
      key = (ok < key) ? ok : key;
    }

    // ---- cross-wave combine via 4 LDS slots, parity double-buffered,
    //      single barrier per step.
    int p = step & 1;
    if (lane == 0) skey[p][w] = key;
    __syncthreads();
    key = skey[p][0];
    #pragma unroll
    for (int k = 1; k < 4; ++k) {
      unsigned long long ok = skey[p][k];
      key = (ok < key) ? ok : key;
    }
    int j = (int)(unsigned)(key & 0xffffffffu);
    int jt = j >> 4;
    int jl = j & 15;

    // record edge with parent BEFORE this step's updates (matches reference).
    // par[jl] read via unrolled select chain -> stays in registers.
    if (jt == tid) {
      int pj = par[0];
      #pragma unroll
      for (int q = 1; q < 16; ++q)
        if (q == jl) pj = par[q];
      edges[step] = make_int2(pj, j);
    }

    // ---- load row j (64B/thread, coalesced) and min-update (all static)
    const T* row = D + (size_t)j * N + base;
    float rv[16];
    #pragma unroll
    for (int u = 0; u < 4; ++u) {
      float4 r = loadRow4(row + u * 4);
      rv[u * 4 + 0] = r.x; rv[u * 4 + 1] = r.y; rv[u * 4 + 2] = r.z; rv[u * 4 + 3] = r.w;
    }
    #pragma unroll
    for (int q = 0; q < 16; ++q) {
      bool upd = rv[q] < md[q];
      md[q] = upd ? rv[q] : md[q];
      par[q] = upd ? j : par[q];
    }
    // md[jl] = INF via unrolled predicated writes (after min-update,
    // matching .at[j].set(inf))
    if (jt == tid) {
      #pragma unroll
      for (int q = 0; q < 16; ++q)
        if (q == jl) md[q] = INF;
    }
  }
}

// ---------- final loss ----------
template <typename T>
__global__ __launch_bounds__(1024) void loss_kernel(const T* __restrict__ Dx,
                                                    const T* __restrict__ Dz,
                                                    const int2* __restrict__ ex,
                                                    const int2* __restrict__ ez,
                                                    float* __restrict__ out) {
  int tid = threadIdx.x;
  float s = 0.f;
  const int M = N - 1;
  for (int e = tid; e < 2 * M; e += 1024) {
    int2 uv = (e < M) ? ex[e] : ez[e - M];
    size_t off = (size_t)uv.x * N + uv.y;
    float dx = toF(Dx[off]);
    float dz = toF(Dz[off]);
    float d = dx - dz;
    s += d * d;
  }
  for (int off = 32; off > 0; off >>= 1) s += __shfl_down(s, off);
  __shared__ float wsum[16];
  int lane = tid & 63, w = tid >> 6;
  if (lane == 0) wsum[w] = s;
  __syncthreads();
  if (tid == 0) {
    float t = 0.f;
    #pragma unroll
    for (int i = 0; i < 16; ++i) t += wsum[i];
    out[0] = 0.5f * t;
  }
}

// ---------- launch ----------
template <typename T>
static void launch_all(const float* x, const float* z, char* ws, float* out,
                       hipStream_t stream) {
  T* Dx = (T*)ws;
  T* Dz = Dx + (size_t)N * N;
  float* sqx = (float*)(Dz + (size_t)N * N);
  float* sqz = sqx + N;
  int2* ex = (int2*)(sqz + N);
  int2* ez = ex + (N - 1);

  sqnorm_kernel<<<N, 256, 0, stream>>>(x, KX, sqx);
  sqnorm_kernel<<<N, 256, 0, stream>>>(z, KZ, sqz);
  dist_gemm_kernel<T><<<NTRI, 256, 0, stream>>>(x, KX, sqx, Dx);
  dist_gemm_kernel<T><<<NTRI, 256, 0, stream>>>(z, KZ, sqz, Dz);
  mst_kernel<T><<<2, 256, 0, stream>>>(Dx, Dz, ex, ez);
  loss_kernel<T><<<1, 1024, 0, stream>>>(Dx, Dz, ex, ez, out);
}

extern "C" void kernel_launch(void* const* d_in, const int* in_sizes, int n_in,
                              void* d_out, int out_size, void* d_ws, size_t ws_size,
                              hipStream_t stream) {
  const float* x = (const float*)d_in[0];
  const float* z = (const float*)d_in[1];
  float* out = (float*)d_out;
  char* ws = (char*)d_ws;

  size_t need_f32 = (size_t)2 * N * N * sizeof(float) + 2 * N * sizeof(float)
                  + (size_t)2 * (N - 1) * sizeof(int2);
  if (ws_size >= need_f32) {
    launch_all<float>(x, z, ws, out, stream);
  } else {
    launch_all<__half>(x, z, ws, out, stream);
  }
}

// Round 4
// 4351.921 us; speedup vs baseline: 1.7336x; 1.4128x over previous
//
#include <hip/hip_runtime.h>
#include <hip/hip_fp16.h>

#define N 4096
#define KX 3072
#define KZ 128
#define NB (N / 64)
#define NTRI (NB * (NB + 1) / 2)

// ---------- helpers ----------
__device__ __forceinline__ float2 up2(unsigned v) {
  __half2 h = __builtin_bit_cast(__half2, v);
  return __half22float2(h);
}

// DPP-based partial min (within 16-lane rows); CTRL is a compile-time constant.
template <int CTRL>
__device__ __forceinline__ float dpp_fmin(float x) {
  int y = __builtin_amdgcn_update_dpp(0, __float_as_int(x), CTRL, 0xF, 0xF, true);
  return fminf(x, __int_as_float(y));
}

// ---------- row squared norms ----------
__global__ __launch_bounds__(256) void sqnorm_kernel(const float* __restrict__ X, int K,
                                                     float* __restrict__ sq) {
  int row = blockIdx.x;
  const float4* xr = (const float4*)(X + (size_t)row * K);
  float s = 0.f;
  int n4 = K >> 2;
  for (int i = threadIdx.x; i < n4; i += 256) {
    float4 v = xr[i];
    s += v.x * v.x + v.y * v.y + v.z * v.z + v.w * v.w;
  }
  for (int off = 32; off > 0; off >>= 1) s += __shfl_down(s, off);
  __shared__ float wsum[4];
  int lane = threadIdx.x & 63, w = threadIdx.x >> 6;
  if (lane == 0) wsum[w] = s;
  __syncthreads();
  if (threadIdx.x == 0) {
    float t = 0.f;
    #pragma unroll
    for (int i = 0; i < 4; ++i) t += wsum[i];
    sq[row] = t;
  }
}

// ---------- fused distance GEMM: D = sqrt(relu(sq_i + sq_j - 2*X@X^T)), half out ----------
__global__ __launch_bounds__(256) void dist_gemm_kernel(const float* __restrict__ X, int K,
                                                        const float* __restrict__ sq,
                                                        __half* __restrict__ D) {
  int t = blockIdx.x;
  int br = (int)((sqrtf(8.0f * (float)t + 1.0f) - 1.0f) * 0.5f);
  while ((br + 1) * (br + 2) / 2 <= t) ++br;
  while (br * (br + 1) / 2 > t) --br;
  int bc = t - br * (br + 1) / 2;
  int i0 = br * 64, j0 = bc * 64;

  __shared__ float As[32][68];
  __shared__ float Bs[32][68];

  int tid = threadIdx.x;
  int tx = tid & 15, ty = tid >> 4;

  float acc[4][4] = {};

  for (int k0 = 0; k0 < K; k0 += 32) {
    #pragma unroll
    for (int u = 0; u < 2; ++u) {
      int f = tid + u * 256;   // 0..511
      int m = f >> 3;          // 0..63
      int kc = (f & 7) * 4;    // 0..28
      float4 a = *(const float4*)(X + (size_t)(i0 + m) * K + k0 + kc);
      As[kc + 0][m] = a.x; As[kc + 1][m] = a.y; As[kc + 2][m] = a.z; As[kc + 3][m] = a.w;
      float4 b = *(const float4*)(X + (size_t)(j0 + m) * K + k0 + kc);
      Bs[kc + 0][m] = b.x; Bs[kc + 1][m] = b.y; Bs[kc + 2][m] = b.z; Bs[kc + 3][m] = b.w;
    }
    __syncthreads();
    #pragma unroll
    for (int kk = 0; kk < 32; ++kk) {
      float4 a = *(const float4*)&As[kk][ty * 4];
      float4 b = *(const float4*)&Bs[kk][tx * 4];
      float av[4] = {a.x, a.y, a.z, a.w};
      float bv[4] = {b.x, b.y, b.z, b.w};
      #pragma unroll
      for (int i = 0; i < 4; ++i)
        #pragma unroll
        for (int j = 0; j < 4; ++j)
          acc[i][j] = fmaf(av[i], bv[j], acc[i][j]);
    }
    __syncthreads();
  }

  #pragma unroll
  for (int i = 0; i < 4; ++i) {
    int gi = i0 + ty * 4 + i;
    float sqi = sq[gi];
    #pragma unroll
    for (int j = 0; j < 4; ++j) {
      int gj = j0 + tx * 4 + j;
      float d2 = sqi + sq[gj] - 2.0f * acc[i][j];
      float d = sqrtf(fmaxf(d2, 0.0f));
      __half h = __float2half(d);
      D[(size_t)gi * N + gj] = h;
      D[(size_t)gj * N + gi] = h;
    }
  }
}

// ---------- MST (exact replication of the reference scan) ----------
// block 0 -> Dx, block 1 -> Dz. 512 threads (8 waves), 8 nodes/thread, ALL state
// in named scalars (scratch impossible). Adjacent-pair min tree (left index <
// right index at every level, strict '<' keep-left) = exact first-index argmin.
// Wave reduce: 4 DPP stages + ds_swizzle(xor16) + shfl_xor(32) on the VALUE
// only, then ballot picks the lowest lane (== lowest node index on ties).
__global__ __launch_bounds__(512) void mst_kernel(const __half* __restrict__ Dx,
                                                  const __half* __restrict__ Dz,
                                                  int2* __restrict__ ex,
                                                  int2* __restrict__ ez) {
  const __half* __restrict__ D = (blockIdx.x == 0) ? Dx : Dz;
  int2* __restrict__ edges = (blockIdx.x == 0) ? ex : ez;
  const float INF = __builtin_inff();

  int tid = threadIdx.x;      // 0..511
  int lane = tid & 63;
  int w = tid >> 6;           // wave 0..7
  int base = tid * 8;         // nodes [base, base+8)

  float md0, md1, md2, md3, md4, md5, md6, md7;
  int par0 = 0, par1 = 0, par2 = 0, par3 = 0, par4 = 0, par5 = 0, par6 = 0, par7 = 0;
  {
    uint4 u = *(const uint4*)(D + base);
    float2 f;
    f = up2(u.x); md0 = f.x; md1 = f.y;
    f = up2(u.y); md2 = f.x; md3 = f.y;
    f = up2(u.z); md4 = f.x; md5 = f.y;
    f = up2(u.w); md6 = f.x; md7 = f.y;
  }
  if (tid == 0) md0 = INF;  // node 0 starts in tree

  __shared__ unsigned long long skey[2][8];

  for (int step = 0; step < N - 1; ++step) {
    // ---- local argmin over 8 named scalars (exact lowest-index tiebreak)
    bool c;
    c = md1 < md0; float v01 = c ? md1 : md0; int i01 = c ? 1 : 0;
    c = md3 < md2; float v23 = c ? md3 : md2; int i23 = c ? 3 : 2;
    c = md5 < md4; float v45 = c ? md5 : md4; int i45 = c ? 5 : 4;
    c = md7 < md6; float v67 = c ? md7 : md6; int i67 = c ? 7 : 6;
    c = v23 < v01; float v03 = c ? v23 : v01; int i03 = c ? i23 : i01;
    c = v67 < v45; float v47 = c ? v67 : v45; int i47 = c ? i67 : i45;
    c = v47 < v03; float bv = c ? v47 : v03;  int bi = base + (c ? i47 : i03);

    // ---- wave-wide min of the value
    float mv = bv;
    mv = dpp_fmin<0xB1>(mv);    // quad_perm [1,0,3,2]  : xor 1
    mv = dpp_fmin<0x4E>(mv);    // quad_perm [2,3,0,1]  : xor 2
    mv = dpp_fmin<0x141>(mv);   // row_half_mirror      : xor 4
    mv = dpp_fmin<0x140>(mv);   // row_mirror           : xor 8
    {
      int t = __builtin_amdgcn_ds_swizzle(__float_as_int(mv), 0x401F);  // xor 16
      mv = fminf(mv, __int_as_float(t));
    }
    mv = fminf(mv, __shfl_xor(mv, 32));  // xor 32

    // lowest lane holding the min == lowest node index (lane order = index order)
    unsigned long long ball = __ballot(bv == mv);
    int first = __ffsll(ball) - 1;
    int p = step & 1;
    if (lane == first)
      skey[p][w] = ((unsigned long long)__float_as_uint(mv) << 32) | (unsigned)bi;
    __syncthreads();

    // ---- cross-wave combine: u64 min over 8 slots (ties -> lowest index)
    unsigned long long key = skey[p][0];
    #pragma unroll
    for (int k = 1; k < 8; ++k) {
      unsigned long long o = skey[p][k];
      key = (o < key) ? o : key;
    }
    int j = (int)(unsigned)key;
    int jt = j >> 3, jl = j & 7;

    // record edge with parent BEFORE this step's updates (matches reference)
    if (jt == tid) {
      int pj = (jl == 0) ? par0 : (jl == 1) ? par1 : (jl == 2) ? par2 :
               (jl == 3) ? par3 : (jl == 4) ? par4 : (jl == 5) ? par5 :
               (jl == 6) ? par6 : par7;
      edges[step] = make_int2(pj, j);
    }

    // ---- load row j (16 B/thread, coalesced, half) and min-update
    uint4 u = *(const uint4*)(D + (size_t)j * N + base);
    float2 f;
    float r0, r1, r2, r3, r4, r5, r6, r7;
    f = up2(u.x); r0 = f.x; r1 = f.y;
    f = up2(u.y); r2 = f.x; r3 = f.y;
    f = up2(u.z); r4 = f.x; r5 = f.y;
    f = up2(u.w); r6 = f.x; r7 = f.y;

    #define UPD(q, rq) { bool up = rq < md##q; md##q = up ? rq : md##q; par##q = up ? j : par##q; }
    UPD(0, r0) UPD(1, r1) UPD(2, r2) UPD(3, r3)
    UPD(4, r4) UPD(5, r5) UPD(6, r6) UPD(7, r7)
    #undef UPD

    // md[jl] = INF after min-update (matches .at[j].set(inf))
    if (jt == tid) {
      if      (jl == 0) md0 = INF;
      else if (jl == 1) md1 = INF;
      else if (jl == 2) md2 = INF;
      else if (jl == 3) md3 = INF;
      else if (jl == 4) md4 = INF;
      else if (jl == 5) md5 = INF;
      else if (jl == 6) md6 = INF;
      else              md7 = INF;
    }
  }
}

// ---------- final loss ----------
__global__ __launch_bounds__(1024) void loss_kernel(const __half* __restrict__ Dx,
                                                    const __half* __restrict__ Dz,
                                                    const int2* __restrict__ ex,
                                                    const int2* __restrict__ ez,
                                                    float* __restrict__ out) {
  int tid = threadIdx.x;
  float s = 0.f;
  const int M = N - 1;
  for (int e = tid; e < 2 * M; e += 1024) {
    int2 uv = (e < M) ? ex[e] : ez[e - M];
    size_t off = (size_t)uv.x * N + uv.y;
    float dx = __half2float(Dx[off]);
    float dz = __half2float(Dz[off]);
    float d = dx - dz;
    s += d * d;
  }
  for (int off = 32; off > 0; off >>= 1) s += __shfl_down(s, off);
  __shared__ float wsum[16];
  int lane = tid & 63, w = tid >> 6;
  if (lane == 0) wsum[w] = s;
  __syncthreads();
  if (tid == 0) {
    float t = 0.f;
    #pragma unroll
    for (int i = 0; i < 16; ++i) t += wsum[i];
    out[0] = 0.5f * t;
  }
}

// ---------- launch ----------
extern "C" void kernel_launch(void* const* d_in, const int* in_sizes, int n_in,
                              void* d_out, int out_size, void* d_ws, size_t ws_size,
                              hipStream_t stream) {
  const float* x = (const float*)d_in[0];
  const float* z = (const float*)d_in[1];
  float* out = (float*)d_out;
  char* ws = (char*)d_ws;

  __half* Dx = (__half*)ws;
  __half* Dz = Dx + (size_t)N * N;
  float* sqx = (float*)(Dz + (size_t)N * N);
  float* sqz = sqx + N;
  int2* ex = (int2*)(sqz + N);
  int2* ez = ex + (N - 1);

  sqnorm_kernel<<<N, 256, 0, stream>>>(x, KX, sqx);
  sqnorm_kernel<<<N, 256, 0, stream>>>(z, KZ, sqz);
  dist_gemm_kernel<<<NTRI, 256, 0, stream>>>(x, KX, sqx, Dx);
  dist_gemm_kernel<<<NTRI, 256, 0, stream>>>(z, KZ, sqz, Dz);
  mst_kernel<<<2, 512, 0, stream>>>(Dx, Dz, ex, ez);
  loss_kernel<<<1, 1024, 0, stream>>>(Dx, Dz, ex, ez, out);
}